// Round 14
// baseline (418.029 us; speedup 1.0000x reference)
//
#include <hip/hip_runtime.h>
#include <cstdint>
#include <cstddef>

// GraphSAGE 3-layer, mean aggregation.
// R14: A-staging made CONTIGUOUS. R11 vs R13 solved as 2 equations: contiguous
// global_load_lds ~61 cyc/KB, scattered-64B sources ~4x worse; both kernels
// staging-bound. A operands (aggb, h-copies, xb) are produced by our own
// kernels -> now written in the exact LDS tile image (k-step-major 8KB tiles,
// swizzle baked in): gemm A staging = linear 1KB copies like W. Gather keeps
// a linear copy (dual-write in epilogue/convert; +25MB writes). Bit-identical
// math vs R13. GEMM structure unchanged (128x128, m97 2-barrier pipeline).

typedef __bf16 bf16x8 __attribute__((ext_vector_type(8)));
typedef __bf16 bf16x4 __attribute__((ext_vector_type(4)));
typedef float  f32x4  __attribute__((ext_vector_type(4)));

static inline size_t align_up(size_t x, size_t a) { return (x + a - 1) / a * a; }

__device__ __forceinline__ void gload_lds16(const void* g, void* l) {
    __builtin_amdgcn_global_load_lds(
        (const __attribute__((address_space(1))) void*)g,
        (__attribute__((address_space(3))) void*)l, 16, 0, 0);
}

// Tiled (LDS-image) offset in uint16 units for a bf16 matrix with S1 k-steps:
// panel = node>>7, r = node&127, k -> step s = k>>5, kq = (k>>3)&3, pos = k&7.
// step tile 8KB: (r>>4)*1024B + (r&15)*64B + slot*16B, slot = kq ^ ((r>>1)&3).
template<int S1>
__device__ __forceinline__ size_t tiled_off16(int node, int k) {
    int panel = node >> 7, r = node & 127;
    int s = k >> 5, kq = (k >> 3) & 3, pos = k & 7;
    int slot = kq ^ ((r >> 1) & 3);
    return (size_t)panel * (S1 * 4096) + (size_t)s * 4096
         + (r >> 4) * 512 + (r & 15) * 32 + slot * 8 + pos;
}

__global__ void deg_kernel(const int* __restrict__ dst, int* __restrict__ deg, int E) {
    int i = blockIdx.x * blockDim.x + threadIdx.x;
    if (i < E) atomicAdd(&deg[dst[i]], 1);
}

// ---- 3-phase scan: deg -> rowptr (exclusive), cursor, inv_deg ----
__global__ void scan_a(const int* __restrict__ deg, int* __restrict__ blocksums, int n) {
    __shared__ int ts[256];
    int t = threadIdx.x;
    int base = blockIdx.x * 1024 + t * 4;
    int s = 0;
    #pragma unroll
    for (int j = 0; j < 4; ++j) if (base + j < n) s += deg[base + j];
    ts[t] = s;
    __syncthreads();
    #pragma unroll
    for (int off = 128; off >= 1; off >>= 1) {
        if (t < off) ts[t] += ts[t + off];
        __syncthreads();
    }
    if (t == 0) blocksums[blockIdx.x] = ts[0];
}

__global__ void scan_b(const int* __restrict__ blocksums, int* __restrict__ blockoff,
                       int NB, int* __restrict__ rowptr_n) {
    __shared__ int ts[256];
    int t = threadIdx.x;
    int v = (t < NB) ? blocksums[t] : 0;
    ts[t] = v;
    __syncthreads();
    for (int off = 1; off < 256; off <<= 1) {
        int u = (t >= off) ? ts[t - off] : 0;
        __syncthreads();
        ts[t] += u;
        __syncthreads();
    }
    if (t < NB) blockoff[t] = ts[t] - v;
    if (t == 255) *rowptr_n = ts[255];
}

__global__ void scan_c(const int* __restrict__ deg, const int* __restrict__ blockoff,
                       int* __restrict__ rowptr, int* __restrict__ cursor,
                       float* __restrict__ inv_deg, int n) {
    __shared__ int ts[256];
    int t = threadIdx.x;
    int base = blockIdx.x * 1024 + t * 4;
    int d[4];
    int s = 0;
    #pragma unroll
    for (int j = 0; j < 4; ++j) {
        d[j] = (base + j < n) ? deg[base + j] : 0;
        s += d[j];
    }
    ts[t] = s;
    __syncthreads();
    for (int off = 1; off < 256; off <<= 1) {
        int u = (t >= off) ? ts[t - off] : 0;
        __syncthreads();
        ts[t] += u;
        __syncthreads();
    }
    int ex = ts[t] - s + blockoff[blockIdx.x];
    #pragma unroll
    for (int j = 0; j < 4; ++j) {
        if (base + j < n) {
            rowptr[base + j] = ex;
            cursor[base + j] = ex;
            inv_deg[base + j] = d[j] > 0 ? 1.0f / (float)d[j] : 0.0f;
            ex += d[j];
        }
    }
}

__global__ void fill_kernel(const int* __restrict__ src, const int* __restrict__ dst,
                            int* __restrict__ cursor, int* __restrict__ csr, int E) {
    int i = blockIdx.x * blockDim.x + threadIdx.x;
    if (i < E) {
        int p = atomicAdd(&cursor[dst[i]], 1);
        csr[p] = src[i];
    }
}

// fp32 -> bf16 dual-write: linear (for gather) + tiled (for gemm A2).
// One thread per 16B chunk (8 elems): chunk ci -> node = ci>>4, kbase = (ci&15)*8.
__global__ void f32_to_bf16_dual(const float* __restrict__ in, uint16_t* __restrict__ lin,
                                 uint16_t* __restrict__ til, int nchunks) {
    int ci = blockIdx.x * blockDim.x + threadIdx.x;
    if (ci >= nchunks) return;
    int i = ci * 8;
    float4 v0 = *(const float4*)(in + i);
    float4 v1 = *(const float4*)(in + i + 4);
    bf16x8 o;
    o[0] = (__bf16)v0.x; o[1] = (__bf16)v0.y; o[2] = (__bf16)v0.z; o[3] = (__bf16)v0.w;
    o[4] = (__bf16)v1.x; o[5] = (__bf16)v1.y; o[6] = (__bf16)v1.z; o[7] = (__bf16)v1.w;
    *(bf16x8*)(lin + i) = o;
    *(bf16x8*)(til + tiled_off16<4>(ci >> 4, (ci & 15) * 8)) = o;
}

__device__ inline void addq(float* a, uint32_t u0, uint32_t u1, uint32_t u2, uint32_t u3) {
    uint32_t u[4] = {u0, u1, u2, u3};
    #pragma unroll
    for (int i = 0; i < 4; ++i) {
        a[2 * i]     += __uint_as_float(u[i] << 16);
        a[2 * i + 1] += __uint_as_float(u[i] & 0xffff0000u);
    }
}

// bf16 gather aggregation: reads LINEAR hb; writes TILED aggbT.
template<int C>
__global__ void agg_bf16(const uint16_t* __restrict__ hb, const int* __restrict__ rowptr,
                         const int* __restrict__ csr, const float* __restrict__ inv_deg,
                         uint16_t* __restrict__ aggbT, int n) {
    constexpr int LPN = C / 8;
    constexpr int NPB = 256 / LPN;
    constexpr int S1 = C / 32;
    int node = blockIdx.x * NPB + (int)(threadIdx.x / LPN);
    if (node >= n) return;
    int sub = threadIdx.x % LPN;
    int b = rowptr[node], e = rowptr[node + 1];
    float acc[8] = {0.f, 0.f, 0.f, 0.f, 0.f, 0.f, 0.f, 0.f};
    const uint4* h4 = (const uint4*)hb;
    int k = b;
    for (; k + 3 < e; k += 4) {
        int s0 = csr[k], s1 = csr[k + 1], s2 = csr[k + 2], s3 = csr[k + 3];
        uint4 q0 = h4[(size_t)s0 * LPN + sub];
        uint4 q1 = h4[(size_t)s1 * LPN + sub];
        uint4 q2 = h4[(size_t)s2 * LPN + sub];
        uint4 q3 = h4[(size_t)s3 * LPN + sub];
        addq(acc, q0.x, q0.y, q0.z, q0.w);
        addq(acc, q1.x, q1.y, q1.z, q1.w);
        addq(acc, q2.x, q2.y, q2.z, q2.w);
        addq(acc, q3.x, q3.y, q3.z, q3.w);
    }
    for (; k < e; ++k) {
        uint4 q = h4[(size_t)csr[k] * LPN + sub];
        addq(acc, q.x, q.y, q.z, q.w);
    }
    float id = inv_deg[node];
    bf16x8 o;
    #pragma unroll
    for (int j = 0; j < 8; ++j) o[j] = (__bf16)(acc[j] * id);
    *(bf16x8*)(aggbT + tiled_off16<S1>(node, sub * 8)) = o;
}

// Pre-convert W = [Wl; Wr] into per-k-step FRAGMENT-MAJOR bf16 hi/lo planes.
// Step s (BK=32), plane 32KB = [hi 16KB][lo 16KB]; hi: col-group cg (0..15) x
// lane l (0..63) x 16B; (cg,l) 16B = cols cg*16+(l&15), k-quad (l>>4)*8..+7.
__global__ void convert_w(const float* __restrict__ Wl, const float* __restrict__ Wr,
                          uint8_t* __restrict__ Wpre, int K1) {
    int c = threadIdx.x;
    int kbase = blockIdx.x * 4;
    bf16x4 hi4, lo4;
    #pragma unroll
    for (int j = 0; j < 4; ++j) {
        int k = kbase + j;
        float w = (k < K1) ? Wl[(size_t)k * 256 + c] : Wr[(size_t)(k - K1) * 256 + c];
        __bf16 h = (__bf16)w;
        __bf16 l = (__bf16)(w - (float)h);
        hi4[j] = h;
        lo4[j] = l;
    }
    int s = kbase >> 5;
    int kk = kbase & 31;
    int lane = (c & 15) + ((kk >> 3) << 4);
    uint32_t byte = (uint32_t)(c >> 4) * 1024 + (uint32_t)lane * 16 + (uint32_t)(kk & 7) * 2;
    *(bf16x4*)(Wpre + (size_t)s * 32768 + byte) = hi4;
    *(bf16x4*)(Wpre + (size_t)s * 32768 + 16384 + byte) = lo4;
}

__device__ inline uint16_t f2bf(float f) {
    __bf16 h = (__bf16)f;
    union { __bf16 b; uint16_t u; } c;
    c.b = h;
    return c.u;
}

// Fused GEMM: out = relu([A1 | A2] @ (Whi+Wlo) + bias). A operands TILED.
// 128 rows x 128 cols per block; staging = 24 x 1KB fully-linear copies/step.
template<int K1>
__global__ __launch_bounds__(256, 3)
void gemm_mfma(const uint16_t* __restrict__ A1t, const uint16_t* __restrict__ A2t,
               const uint8_t* __restrict__ Wpre, const float* __restrict__ bias,
               float* __restrict__ out, uint16_t* __restrict__ outb,
               uint16_t* __restrict__ outbT, int n) {
    constexpr int S1 = K1 / 32;
    constexpr int NT = 2 * S1;
    __shared__ __align__(16) uint8_t ldsA[2][8192];
    __shared__ __align__(16) uint8_t ldsW[2][16384];

    const int tid = threadIdx.x;
    const int l = tid & 63;
    const int w = tid >> 6;
    const int lr = l & 15;
    const int lg = l >> 4;
    const int panel = blockIdx.x >> 1;
    const int row0 = panel * 128;
    const int cb = blockIdx.x & 1;
    const int wr = w & 1;
    const int cw = w >> 1;

    f32x4 acc[4][4];
    #pragma unroll
    for (int mt = 0; mt < 4; ++mt)
        #pragma unroll
        for (int nt = 0; nt < 4; ++nt)
            acc[mt][nt] = (f32x4)(0.f);

    const int key = (lr >> 1) & 3;
    uint32_t abyte[4];
    #pragma unroll
    for (int mt = 0; mt < 4; ++mt)
        abyte[mt] = (uint32_t)((wr * 64 + mt * 16 + lr) * 64 + ((lg ^ key) << 4));
    uint32_t wrbyte[4];
    #pragma unroll
    for (int nt = 0; nt < 4; ++nt)
        wrbyte[nt] = (uint32_t)((cw * 4 + nt) * 1024 + l * 16);

    // staging: all-linear 1KB blocks. A tile s is an 8KB contiguous span.
    auto stage = [&](int s, int buf) {
        const uint16_t* __restrict__ At = (s < S1) ? A1t : A2t;
        int sl = (s < S1) ? s : s - S1;
        const uint16_t* __restrict__ Abase = At + (size_t)panel * (S1 * 4096) + (size_t)sl * 4096;
        #pragma unroll
        for (int i = 0; i < 2; ++i) {
            int b = w * 2 + i;
            gload_lds16(Abase + b * 512 + l * 8, &ldsA[buf][b * 1024]);
        }
        const uint8_t* __restrict__ Ws = Wpre + (size_t)s * 32768 + (size_t)cb * 8192;
        #pragma unroll
        for (int i = 0; i < 2; ++i) {
            int b = w * 2 + i;
            gload_lds16(Ws + b * 1024 + l * 16, &ldsW[buf][b * 1024]);
            gload_lds16(Ws + 16384 + b * 1024 + l * 16, &ldsW[buf][8192 + b * 1024]);
        }
    };

    auto domfma = [&](int buf) {
        bf16x8 bh[4], bl_[4];
        #pragma unroll
        for (int nt = 0; nt < 4; ++nt) {
            bh[nt]  = *(const bf16x8*)(&ldsW[buf][wrbyte[nt]]);
            bl_[nt] = *(const bf16x8*)(&ldsW[buf][8192 + wrbyte[nt]]);
        }
        #pragma unroll
        for (int mt = 0; mt < 4; ++mt) {
            bf16x8 a = *(const bf16x8*)(&ldsA[buf][abyte[mt]]);
            #pragma unroll
            for (int nt = 0; nt < 4; ++nt) {
                acc[mt][nt] = __builtin_amdgcn_mfma_f32_16x16x32_bf16(a, bh[nt],  acc[mt][nt], 0, 0, 0);
                acc[mt][nt] = __builtin_amdgcn_mfma_f32_16x16x32_bf16(a, bl_[nt], acc[mt][nt], 0, 0, 0);
            }
        }
    };

    stage(0, 0);
    __syncthreads();
    #pragma unroll 1
    for (int s = 0; s < NT; ++s) {
        int buf = s & 1;
        if (s + 1 < NT) stage(s + 1, buf ^ 1);
        domfma(buf);
        __syncthreads();
    }

    // epilogue: D row = row0 + wr*64 + mt*16 + lg*4 + rr,
    //           col = cb*128 + cw*64 + nt*16 + lr
    #pragma unroll
    for (int nt = 0; nt < 4; ++nt) {
        int col = cb * 128 + cw * 64 + nt * 16 + lr;
        float bv = bias[col];
        #pragma unroll
        for (int mt = 0; mt < 4; ++mt) {
            #pragma unroll
            for (int rr = 0; rr < 4; ++rr) {
                int grow = row0 + wr * 64 + mt * 16 + lg * 4 + rr;
                if (grow < n) {
                    float v = fmaxf(acc[mt][nt][rr] + bv, 0.f);
                    uint16_t bvv = f2bf(v);
                    if (out)   out[(size_t)grow * 256 + col] = v;
                    if (outb)  outb[(size_t)grow * 256 + col] = bvv;
                    if (outbT) outbT[tiled_off16<8>(grow, col)] = bvv;
                }
            }
        }
    }
}

extern "C" void kernel_launch(void* const* d_in, const int* in_sizes, int n_in,
                              void* d_out, int out_size, void* d_ws, size_t ws_size,
                              hipStream_t stream) {
    const float* x   = (const float*)d_in[0];
    const int* edge  = (const int*)d_in[1];
    const float* Wl0 = (const float*)d_in[2];
    const float* bl0 = (const float*)d_in[3];
    const float* Wr0 = (const float*)d_in[4];
    const float* Wl1 = (const float*)d_in[5];
    const float* bl1 = (const float*)d_in[6];
    const float* Wr1 = (const float*)d_in[7];
    const float* Wl2 = (const float*)d_in[8];
    const float* bl2 = (const float*)d_in[9];
    const float* Wr2 = (const float*)d_in[10];

    int n = in_sizes[0] / 128;   // 50000
    int E = in_sizes[1] / 2;     // 800000
    int panels = (n + 127) / 128;   // 391
    const int* src = edge;
    const int* dst = edge + E;

    char* wptr = (char*)d_ws;
    auto alloc = [&](size_t bytes) { char* p = wptr; wptr += align_up(bytes, 256); return p; };
    int*      deg    = (int*)alloc((size_t)n * 4);
    int*      rowptr = (int*)alloc(((size_t)n + 1) * 4);
    int*      cursor = (int*)alloc((size_t)n * 4);
    int*      csr    = (int*)alloc((size_t)E * 4);
    float*    invd   = (float*)alloc((size_t)n * 4);
    int*      bsums  = (int*)alloc(256 * 4);
    int*      boff   = (int*)alloc(256 * 4);
    uint8_t*  Wp0    = (uint8_t*)alloc(8 * 32768);
    uint8_t*  Wp1    = (uint8_t*)alloc(16 * 32768);
    uint8_t*  Wp2    = (uint8_t*)alloc(16 * 32768);
    uint16_t* xb     = (uint16_t*)alloc((size_t)panels * 128 * 128 * 2);  // linear
    uint16_t* xbT    = (uint16_t*)alloc((size_t)panels * 4 * 8192);      // tiled (S1=4)
    uint16_t* aggbT  = (uint16_t*)alloc((size_t)panels * 8 * 8192);      // tiled (S1<=8)
    uint16_t* h0b    = (uint16_t*)alloc((size_t)panels * 128 * 256 * 2); // linear
    uint16_t* h0bT   = (uint16_t*)alloc((size_t)panels * 8 * 8192);      // tiled (S1=8)
    uint16_t* h1b    = (uint16_t*)alloc((size_t)panels * 128 * 256 * 2);
    uint16_t* h1bT   = (uint16_t*)alloc((size_t)panels * 8 * 8192);

    int NB = (n + 1023) / 1024;
    hipMemsetAsync(deg, 0, (size_t)n * 4, stream);
    deg_kernel<<<(E + 255) / 256, 256, 0, stream>>>(dst, deg, E);
    scan_a<<<NB, 256, 0, stream>>>(deg, bsums, n);
    scan_b<<<1, 256, 0, stream>>>(bsums, boff, NB, rowptr + n);
    scan_c<<<NB, 256, 0, stream>>>(deg, boff, rowptr, cursor, invd, n);
    fill_kernel<<<(E + 255) / 256, 256, 0, stream>>>(src, dst, cursor, csr, E);

    convert_w<<<2 * 128 / 4, 256, 0, stream>>>(Wl0, Wr0, Wp0, 128);
    convert_w<<<2 * 256 / 4, 256, 0, stream>>>(Wl1, Wr1, Wp1, 256);
    convert_w<<<2 * 256 / 4, 256, 0, stream>>>(Wl2, Wr2, Wp2, 256);

    int nchunks = n * 16;   // 16B chunks of x
    f32_to_bf16_dual<<<(nchunks + 255) / 256, 256, 0, stream>>>(x, xb, xbT, nchunks);

    int gemm_grid = panels * 2;   // 782
    // layer 0: C=128 -> 256
    agg_bf16<128><<<(n + 15) / 16, 256, 0, stream>>>(xb, rowptr, csr, invd, aggbT, n);
    gemm_mfma<128><<<gemm_grid, 256, 0, stream>>>(aggbT, xbT, Wp0, bl0,
                                                  (float*)nullptr, h0b, h0bT, n);
    // layer 1: 256 -> 256
    agg_bf16<256><<<(n + 7) / 8, 256, 0, stream>>>(h0b, rowptr, csr, invd, aggbT, n);
    gemm_mfma<256><<<gemm_grid, 256, 0, stream>>>(aggbT, h0bT, Wp1, bl1,
                                                  (float*)nullptr, h1b, h1bT, n);
    // layer 2: 256 -> 256 (fp32 output to d_out)
    agg_bf16<256><<<(n + 7) / 8, 256, 0, stream>>>(h1b, rowptr, csr, invd, aggbT, n);
    gemm_mfma<256><<<gemm_grid, 256, 0, stream>>>(aggbT, h1bT, Wp2, bl2,
                                                  (float*)d_out, (uint16_t*)nullptr,
                                                  (uint16_t*)nullptr, n);
}

// Round 15
// 349.652 us; speedup vs baseline: 1.1956x; 1.1956x over previous
//
#include <hip/hip_runtime.h>
#include <cstdint>
#include <cstddef>

// GraphSAGE 3-layer, mean aggregation.
// R15: revert R14 (tiled-A staging was a wash: R13's 59.5us/gemm is NOT
// source-pattern-bound -> model corrected). Base = R13 (best, 404us).
// Change: W is single-plane bf16 (lo-plane dropped). Error model calibrated
// against measurement: A-quant predicted 3.9e-3 absmax = measured; W-quant is
// the same magnitude, quadrature -> ~5.5e-3 vs 13.6e-3 threshold. Halves
// MFMA/step (32->16), W staging (16->8KB/step), LDS 48->32KB.
// If gemm only drops ~15%, steps are latency-quantized -> next: fewer steps.

typedef __bf16 bf16x8 __attribute__((ext_vector_type(8)));
typedef __bf16 bf16x4 __attribute__((ext_vector_type(4)));
typedef float  f32x4  __attribute__((ext_vector_type(4)));

static inline size_t align_up(size_t x, size_t a) { return (x + a - 1) / a * a; }

__device__ __forceinline__ void gload_lds16(const void* g, void* l) {
    __builtin_amdgcn_global_load_lds(
        (const __attribute__((address_space(1))) void*)g,
        (__attribute__((address_space(3))) void*)l, 16, 0, 0);
}

__global__ void deg_kernel(const int* __restrict__ dst, int* __restrict__ deg, int E) {
    int i = blockIdx.x * blockDim.x + threadIdx.x;
    if (i < E) atomicAdd(&deg[dst[i]], 1);
}

// ---- 3-phase scan: deg -> rowptr (exclusive), cursor, inv_deg ----
__global__ void scan_a(const int* __restrict__ deg, int* __restrict__ blocksums, int n) {
    __shared__ int ts[256];
    int t = threadIdx.x;
    int base = blockIdx.x * 1024 + t * 4;
    int s = 0;
    #pragma unroll
    for (int j = 0; j < 4; ++j) if (base + j < n) s += deg[base + j];
    ts[t] = s;
    __syncthreads();
    #pragma unroll
    for (int off = 128; off >= 1; off >>= 1) {
        if (t < off) ts[t] += ts[t + off];
        __syncthreads();
    }
    if (t == 0) blocksums[blockIdx.x] = ts[0];
}

__global__ void scan_b(const int* __restrict__ blocksums, int* __restrict__ blockoff,
                       int NB, int* __restrict__ rowptr_n) {
    __shared__ int ts[256];
    int t = threadIdx.x;
    int v = (t < NB) ? blocksums[t] : 0;
    ts[t] = v;
    __syncthreads();
    for (int off = 1; off < 256; off <<= 1) {
        int u = (t >= off) ? ts[t - off] : 0;
        __syncthreads();
        ts[t] += u;
        __syncthreads();
    }
    if (t < NB) blockoff[t] = ts[t] - v;
    if (t == 255) *rowptr_n = ts[255];
}

__global__ void scan_c(const int* __restrict__ deg, const int* __restrict__ blockoff,
                       int* __restrict__ rowptr, int* __restrict__ cursor,
                       float* __restrict__ inv_deg, int n) {
    __shared__ int ts[256];
    int t = threadIdx.x;
    int base = blockIdx.x * 1024 + t * 4;
    int d[4];
    int s = 0;
    #pragma unroll
    for (int j = 0; j < 4; ++j) {
        d[j] = (base + j < n) ? deg[base + j] : 0;
        s += d[j];
    }
    ts[t] = s;
    __syncthreads();
    for (int off = 1; off < 256; off <<= 1) {
        int u = (t >= off) ? ts[t - off] : 0;
        __syncthreads();
        ts[t] += u;
        __syncthreads();
    }
    int ex = ts[t] - s + blockoff[blockIdx.x];
    #pragma unroll
    for (int j = 0; j < 4; ++j) {
        if (base + j < n) {
            rowptr[base + j] = ex;
            cursor[base + j] = ex;
            inv_deg[base + j] = d[j] > 0 ? 1.0f / (float)d[j] : 0.0f;
            ex += d[j];
        }
    }
}

__global__ void fill_kernel(const int* __restrict__ src, const int* __restrict__ dst,
                            int* __restrict__ cursor, int* __restrict__ csr, int E) {
    int i = blockIdx.x * blockDim.x + threadIdx.x;
    if (i < E) {
        int p = atomicAdd(&cursor[dst[i]], 1);
        csr[p] = src[i];
    }
}

// fp32 -> bf16 (RTNE) convert, 8 elems/thread.
__global__ void f32_to_bf16(const float* __restrict__ in, uint16_t* __restrict__ out, int count) {
    int i = (blockIdx.x * blockDim.x + threadIdx.x) * 8;
    if (i >= count) return;
    float4 v0 = *(const float4*)(in + i);
    float4 v1 = *(const float4*)(in + i + 4);
    bf16x8 o;
    o[0] = (__bf16)v0.x; o[1] = (__bf16)v0.y; o[2] = (__bf16)v0.z; o[3] = (__bf16)v0.w;
    o[4] = (__bf16)v1.x; o[5] = (__bf16)v1.y; o[6] = (__bf16)v1.z; o[7] = (__bf16)v1.w;
    *(bf16x8*)(out + i) = o;
}

__device__ inline void addq(float* a, uint32_t u0, uint32_t u1, uint32_t u2, uint32_t u3) {
    uint32_t u[4] = {u0, u1, u2, u3};
    #pragma unroll
    for (int i = 0; i < 4; ++i) {
        a[2 * i]     += __uint_as_float(u[i] << 16);
        a[2 * i + 1] += __uint_as_float(u[i] & 0xffff0000u);
    }
}

// bf16 gather aggregation: C/8 lanes per node, 16B (8 bf16) per lane.
template<int C>
__global__ void agg_bf16(const uint16_t* __restrict__ hb, const int* __restrict__ rowptr,
                         const int* __restrict__ csr, const float* __restrict__ inv_deg,
                         uint16_t* __restrict__ aggb, int n) {
    constexpr int LPN = C / 8;
    constexpr int NPB = 256 / LPN;
    int node = blockIdx.x * NPB + (int)(threadIdx.x / LPN);
    if (node >= n) return;
    int sub = threadIdx.x % LPN;
    int b = rowptr[node], e = rowptr[node + 1];
    float acc[8] = {0.f, 0.f, 0.f, 0.f, 0.f, 0.f, 0.f, 0.f};
    const uint4* h4 = (const uint4*)hb;
    int k = b;
    for (; k + 3 < e; k += 4) {
        int s0 = csr[k], s1 = csr[k + 1], s2 = csr[k + 2], s3 = csr[k + 3];
        uint4 q0 = h4[(size_t)s0 * LPN + sub];
        uint4 q1 = h4[(size_t)s1 * LPN + sub];
        uint4 q2 = h4[(size_t)s2 * LPN + sub];
        uint4 q3 = h4[(size_t)s3 * LPN + sub];
        addq(acc, q0.x, q0.y, q0.z, q0.w);
        addq(acc, q1.x, q1.y, q1.z, q1.w);
        addq(acc, q2.x, q2.y, q2.z, q2.w);
        addq(acc, q3.x, q3.y, q3.z, q3.w);
    }
    for (; k < e; ++k) {
        uint4 q = h4[(size_t)csr[k] * LPN + sub];
        addq(acc, q.x, q.y, q.z, q.w);
    }
    float id = inv_deg[node];
    bf16x8 o;
    #pragma unroll
    for (int j = 0; j < 8; ++j) o[j] = (__bf16)(acc[j] * id);
    *(bf16x8*)(aggb + (size_t)node * C + sub * 8) = o;
}

// Pre-convert W = [Wl; Wr] into per-k-step FRAGMENT-MAJOR bf16 planes (hi only).
// Step s (BK=32), plane 16KB: col-group cg (0..15) x lane l (0..63) x 16B;
// (cg,l) 16B = cols cg*16+(l&15), k-quad (l>>4)*8..+7.
__global__ void convert_w(const float* __restrict__ Wl, const float* __restrict__ Wr,
                          uint8_t* __restrict__ Wpre, int K1) {
    int c = threadIdx.x;        // col 0..255
    int kbase = blockIdx.x * 4; // 4 consecutive k
    bf16x4 hi4;
    #pragma unroll
    for (int j = 0; j < 4; ++j) {
        int k = kbase + j;
        float w = (k < K1) ? Wl[(size_t)k * 256 + c] : Wr[(size_t)(k - K1) * 256 + c];
        hi4[j] = (__bf16)w;
    }
    int s = kbase >> 5;
    int kk = kbase & 31;
    int lane = (c & 15) + ((kk >> 3) << 4);
    uint32_t byte = (uint32_t)(c >> 4) * 1024 + (uint32_t)lane * 16 + (uint32_t)(kk & 7) * 2;
    *(bf16x4*)(Wpre + (size_t)s * 16384 + byte) = hi4;
}

__device__ inline uint16_t f2bf(float f) {
    __bf16 h = (__bf16)f;
    union { __bf16 b; uint16_t u; } c;
    c.b = h;
    return c.u;
}

// Fused GEMM: out = relu([A1 | A2] @ W + bias), A row-major bf16, W bf16.
// 128 rows x 128 cols per block (bid>>1 = row panel, bid&1 = col half);
// 4 waves, wave w: rows (w&1)*64, cols (w>>1)*64. m97 pipeline: per step
// stage(s+1, buf^1) = A 8KB + W 8KB via global_load_lds (4 x 16B/thread),
// then ds_read + 16 MFMA, ONE barrier.
template<int K1>
__global__ __launch_bounds__(256, 3)
void gemm_mfma(const uint16_t* __restrict__ A1, const uint16_t* __restrict__ A2,
               const uint8_t* __restrict__ Wpre, const float* __restrict__ bias,
               float* __restrict__ out, uint16_t* __restrict__ outb, int n) {
    constexpr int S1 = K1 / 32;
    constexpr int NT = 2 * S1;          // 8 or 16
    __shared__ __align__(16) uint8_t ldsA[2][8192];   // 128 rows x 64B
    __shared__ __align__(16) uint8_t ldsW[2][8192];   // 128 cols x 64B (frag-major)

    const int tid = threadIdx.x;
    const int l = tid & 63;
    const int w = tid >> 6;
    const int lr = l & 15;
    const int lg = l >> 4;
    const int row0 = (blockIdx.x >> 1) * 128;
    const int cb = blockIdx.x & 1;       // col half (128 cols)
    const int wr = w & 1;                // wave row half (64 rows)
    const int cw = w >> 1;               // wave col group (64 cols)

    f32x4 acc[4][4];
    #pragma unroll
    for (int mt = 0; mt < 4; ++mt)
        #pragma unroll
        for (int nt = 0; nt < 4; ++nt)
            acc[mt][nt] = (f32x4)(0.f);

    // A fragment read offsets (swizzled): row r = wr*64+mt*16+lr,
    // slot = lg ^ ((r>>1)&3) = lg ^ ((lr>>1)&3).
    const int key = (lr >> 1) & 3;
    uint32_t abyte[4];
    #pragma unroll
    for (int mt = 0; mt < 4; ++mt)
        abyte[mt] = (uint32_t)((wr * 64 + mt * 16 + lr) * 64 + ((lg ^ key) << 4));
    // W fragment read offsets (fragment-major, conflict-free): local cg = cw*4+nt
    uint32_t wrbyte[4];
    #pragma unroll
    for (int nt = 0; nt < 4; ++nt)
        wrbyte[nt] = (uint32_t)((cw * 4 + nt) * 1024 + l * 16);

    // staging: 16 x 1KB wave-uniform blocks per step; wave w stages
    // A blocks {2w,2w+1}, W blocks {2w,2w+1}.
    auto stage = [&](int s, int buf) {
        const uint16_t* __restrict__ A = (s < S1) ? A1 : A2;
        int kl = ((s < S1) ? s : s - S1) * 32;
        #pragma unroll
        for (int i = 0; i < 2; ++i) {
            int b = w * 2 + i;                     // A block 0..7
            int r = b * 16 + (l >> 2);             // row 0..127
            int kq = (l & 3) ^ ((r >> 1) & 3);     // pre-swizzled source k-quad
            gload_lds16(A + (size_t)(row0 + r) * K1 + kl + kq * 8,
                        &ldsA[buf][b * 1024]);
        }
        const uint8_t* __restrict__ Ws = Wpre + (size_t)s * 16384 + (size_t)cb * 8192;
        #pragma unroll
        for (int i = 0; i < 2; ++i) {
            int b = w * 2 + i;                     // W block 0..7
            gload_lds16(Ws + b * 1024 + l * 16, &ldsW[buf][b * 1024]);
        }
    };

    auto domfma = [&](int buf) {
        bf16x8 bh[4];
        #pragma unroll
        for (int nt = 0; nt < 4; ++nt)
            bh[nt] = *(const bf16x8*)(&ldsW[buf][wrbyte[nt]]);
        #pragma unroll
        for (int mt = 0; mt < 4; ++mt) {
            bf16x8 a = *(const bf16x8*)(&ldsA[buf][abyte[mt]]);
            #pragma unroll
            for (int nt = 0; nt < 4; ++nt)
                acc[mt][nt] = __builtin_amdgcn_mfma_f32_16x16x32_bf16(a, bh[nt], acc[mt][nt], 0, 0, 0);
        }
    };

    stage(0, 0);
    __syncthreads();
    #pragma unroll 1
    for (int s = 0; s < NT; ++s) {
        int buf = s & 1;
        if (s + 1 < NT) stage(s + 1, buf ^ 1);   // in flight over MFMAs
        domfma(buf);
        __syncthreads();
    }

    // epilogue: D row = row0 + wr*64 + mt*16 + lg*4 + rr,
    //           col = cb*128 + cw*64 + nt*16 + lr (m89-verified)
    #pragma unroll
    for (int nt = 0; nt < 4; ++nt) {
        int col = cb * 128 + cw * 64 + nt * 16 + lr;
        float bv = bias[col];
        #pragma unroll
        for (int mt = 0; mt < 4; ++mt) {
            #pragma unroll
            for (int rr = 0; rr < 4; ++rr) {
                int grow = row0 + wr * 64 + mt * 16 + lg * 4 + rr;
                if (grow < n) {
                    float v = fmaxf(acc[mt][nt][rr] + bv, 0.f);
                    if (out)  out[(size_t)grow * 256 + col] = v;
                    if (outb) outb[(size_t)grow * 256 + col] = f2bf(v);
                }
            }
        }
    }
}

extern "C" void kernel_launch(void* const* d_in, const int* in_sizes, int n_in,
                              void* d_out, int out_size, void* d_ws, size_t ws_size,
                              hipStream_t stream) {
    const float* x   = (const float*)d_in[0];
    const int* edge  = (const int*)d_in[1];
    const float* Wl0 = (const float*)d_in[2];
    const float* bl0 = (const float*)d_in[3];
    const float* Wr0 = (const float*)d_in[4];
    const float* Wl1 = (const float*)d_in[5];
    const float* bl1 = (const float*)d_in[6];
    const float* Wr1 = (const float*)d_in[7];
    const float* Wl2 = (const float*)d_in[8];
    const float* bl2 = (const float*)d_in[9];
    const float* Wr2 = (const float*)d_in[10];

    int n = in_sizes[0] / 128;   // 50000
    int E = in_sizes[1] / 2;     // 800000
    int npad = n + 128;
    const int* src = edge;
    const int* dst = edge + E;

    char* wptr = (char*)d_ws;
    auto alloc = [&](size_t bytes) { char* p = wptr; wptr += align_up(bytes, 256); return p; };
    int*      deg    = (int*)alloc((size_t)n * 4);
    int*      rowptr = (int*)alloc(((size_t)n + 1) * 4);
    int*      cursor = (int*)alloc((size_t)n * 4);
    int*      csr    = (int*)alloc((size_t)E * 4);
    float*    invd   = (float*)alloc((size_t)n * 4);
    int*      bsums  = (int*)alloc(256 * 4);
    int*      boff   = (int*)alloc(256 * 4);
    uint8_t*  Wp0    = (uint8_t*)alloc(8 * 16384);    // 8 steps x 16KB
    uint8_t*  Wp1    = (uint8_t*)alloc(16 * 16384);   // 16 steps x 16KB
    uint8_t*  Wp2    = (uint8_t*)alloc(16 * 16384);
    uint16_t* xb     = (uint16_t*)alloc((size_t)npad * 128 * 2);
    uint16_t* aggb   = (uint16_t*)alloc((size_t)npad * 256 * 2);
    uint16_t* h0b    = (uint16_t*)alloc((size_t)npad * 256 * 2);
    uint16_t* h1b    = (uint16_t*)alloc((size_t)npad * 256 * 2);

    int NB = (n + 1023) / 1024;
    hipMemsetAsync(deg, 0, (size_t)n * 4, stream);
    deg_kernel<<<(E + 255) / 256, 256, 0, stream>>>(dst, deg, E);
    scan_a<<<NB, 256, 0, stream>>>(deg, bsums, n);
    scan_b<<<1, 256, 0, stream>>>(bsums, boff, NB, rowptr + n);
    scan_c<<<NB, 256, 0, stream>>>(deg, boff, rowptr, cursor, invd, n);
    fill_kernel<<<(E + 255) / 256, 256, 0, stream>>>(src, dst, cursor, csr, E);

    convert_w<<<2 * 128 / 4, 256, 0, stream>>>(Wl0, Wr0, Wp0, 128);
    convert_w<<<2 * 256 / 4, 256, 0, stream>>>(Wl1, Wr1, Wp1, 256);
    convert_w<<<2 * 256 / 4, 256, 0, stream>>>(Wl2, Wr2, Wp2, 256);

    int cx = n * 128;
    f32_to_bf16<<<(cx / 8 + 255) / 256, 256, 0, stream>>>(x, xb, cx);

    int gemm_grid = ((n + 127) / 128) * 2;   // 782
    // layer 0: C=128 -> 256
    agg_bf16<128><<<(n + 15) / 16, 256, 0, stream>>>(xb, rowptr, csr, invd, aggb, n);
    gemm_mfma<128><<<gemm_grid, 256, 0, stream>>>(aggb, xb, Wp0, bl0, (float*)nullptr, h0b, n);
    // layer 1: 256 -> 256
    agg_bf16<256><<<(n + 7) / 8, 256, 0, stream>>>(h0b, rowptr, csr, invd, aggb, n);
    gemm_mfma<256><<<gemm_grid, 256, 0, stream>>>(aggb, h0b, Wp1, bl1, (float*)nullptr, h1b, n);
    // layer 2: 256 -> 256 (fp32 output to d_out)
    agg_bf16<256><<<(n + 7) / 8, 256, 0, stream>>>(h1b, rowptr, csr, invd, aggb, n);
    gemm_mfma<256><<<gemm_grid, 256, 0, stream>>>(aggb, h1b, Wp2, bl2, (float*)d_out, (uint16_t*)nullptr, n);
}